// Round 1
// 204.403 us; speedup vs baseline: 1.0734x; 1.0734x over previous
//
#include <hip/hip_runtime.h>
#include <stdint.h>

// Correlation via MFMA. out[b,(dy+4)*9+(dx+4),y,x] = (1/128) sum_c F[c,y,x]*S[c,y+dy,x+dx]
//
// R5: single fused kernel (prepass ELIMINATED — it was ~127us of the 219us total).
//  - second is gathered fp32->bf16 directly into LDS per 32-channel K-chunk, using the
//    same coalesced pattern as the A-frag gather (16 lanes x 4B = 64B per channel plane).
//    LDS layout + XOR swizzle identical to R4 (known correct).
//  - 24 gather dwords for chunk kc+1 issued right after the barrier; packed+written at
//    the top of the next iteration -> HBM latency hides under the MFMA phase.
//  - Epilogue rewritten: per-wave LDS transpose (reuses smem after final barrier,
//    3 chunks of 3 dy, pitch 20 floats) -> all global stores are coalesced float4,
//    each 64B line fully written by the block. R4's scattered 4B stores caused
//    WRITE_SIZE = 128MB vs 40MB ideal (3.2x amplification).
// LESSON (R2): acc[] only ever indexed by fully-unrolled loop vars.

typedef __attribute__((ext_vector_type(8))) short bf16x8;
typedef __attribute__((ext_vector_type(4))) float f32x4;

constexpr int Bn = 8, Cn = 128, Hn = 96, Wn = 160;
constexpr int CHS = Hn * Wn;

__device__ __forceinline__ uint32_t bf16rne(float f) {
    uint32_t u = __float_as_uint(f);
    return (u + 0x7FFFu + ((u >> 16) & 1u)) >> 16;
}
__device__ __forceinline__ uint32_t pk(float a, float b) {
    return bf16rne(a) | (bf16rne(b) << 16);
}

__global__ __launch_bounds__(1024)
void corrfused(const float* __restrict__ first, const float* __restrict__ second,
               float* __restrict__ out)
{
    __shared__ uint4 smem[16 * 48 * 4];   // 48 KB: [row][xw][4 swizzled octs]

    const int tid  = threadIdx.x;
    const int w    = tid >> 6;
    const int lane = tid & 63;
    const int quad = lane >> 4;
    const int n16  = lane & 15;
    const int s    = w & 1;               // strip within tile
    const int r    = w >> 1;              // output row within group
    const int x0   = blockIdx.x * 32;
    const int y0   = blockIdx.y * 8;
    const int b    = blockIdx.z;
    const int y    = y0 + r;
    const int x0s  = x0 + 16 * s;

    // ---- A-frags: first[b][32kc+8quad+j][y][x0s+n16], packed bf16 ----
    bf16x8 aF[4];
    {
        const float* fp = first + (size_t)b * Cn * CHS + (size_t)y * Wn + x0s + n16;
        #pragma unroll
        for (int kc = 0; kc < 4; ++kc) {
            float f[8];
            #pragma unroll
            for (int j = 0; j < 8; ++j)
                f[j] = fp[(size_t)(32 * kc + 8 * quad + j) * CHS];
            union { uint32_t u[4]; bf16x8 v; } cv;
            cv.u[0] = pk(f[0], f[1]); cv.u[1] = pk(f[2], f[3]);
            cv.u[2] = pk(f[4], f[5]); cv.u[3] = pk(f[6], f[7]);
            aF[kc] = cv.v;
        }
    }

    // ---- staging descriptors: 3072 octs (16 rows x 48 px x 4 q), 3 per thread.
    //      slot (row,xw,q) covers channels 32kc+8q..+7 of second at (y0+row-4, x0+xw-8).
    const float* sb = second + (size_t)b * Cn * CHS;
    int goff[3], lpos[3];
    bool val[3];
    #pragma unroll
    for (int i = 0; i < 3; ++i) {
        int e = tid + i * 1024;
        int row = e / 192, rem = e % 192;
        int xw = rem >> 2, q = rem & 3;
        int gy = y0 + row - 4, gx = x0 + xw - 8;
        val[i]  = (gy >= 0) && (gy < Hn) && (gx >= 0) && (gx < Wn);
        goff[i] = val[i] ? (8 * q * CHS + gy * Wn + gx) : 0;   // clamped-safe addr
        lpos[i] = (row * 48 + xw) * 4 + ((q + xw + (xw >> 2)) & 3);
    }

    // ---- B-frag lane offsets (row-invariant part) ----
    int bo[2];
    #pragma unroll
    for (int t = 0; t < 2; ++t) {
        int xwr = 16 * (s + t) + n16;
        bo[t] = xwr * 4 + ((quad + xwr + (xwr >> 2)) & 3);
    }

    f32x4 acc[9][2];
    #pragma unroll
    for (int dy = 0; dy < 9; ++dy)
        #pragma unroll
        for (int t = 0; t < 2; ++t)
            acc[dy][t] = (f32x4){0.f, 0.f, 0.f, 0.f};

    // prologue: gather loads for chunk 0 (8 strided dwords per slot, coalesced
    // 64B per 16-lane group per channel plane)
    float fr[3][8];
    #pragma unroll
    for (int i = 0; i < 3; ++i)
        #pragma unroll
        for (int j = 0; j < 8; ++j)
            fr[i][j] = sb[goff[i] + (size_t)j * CHS];

    #pragma unroll
    for (int kc = 0; kc < 4; ++kc) {
        // pack the in-flight fp32 gather to bf16 octs and write LDS
        #pragma unroll
        for (int i = 0; i < 3; ++i) {
            uint4 o;
            o.x = pk(fr[i][0], fr[i][1]); o.y = pk(fr[i][2], fr[i][3]);
            o.z = pk(fr[i][4], fr[i][5]); o.w = pk(fr[i][6], fr[i][7]);
            if (!val[i]) o = make_uint4(0u, 0u, 0u, 0u);
            smem[lpos[i]] = o;
        }
        __syncthreads();
        // issue next chunk's gather; lands while MFMAs run
        if (kc < 3) {
            #pragma unroll
            for (int i = 0; i < 3; ++i)
                #pragma unroll
                for (int j = 0; j < 8; ++j)
                    fr[i][j] = sb[goff[i] + (size_t)(32 * (kc + 1) + j) * CHS];
        }
        #pragma unroll
        for (int dy = 0; dy < 9; ++dy) {
            const int rb = (r + dy) * 192;        // staged row base (oct units)
            #pragma unroll
            for (int t = 0; t < 2; ++t) {
                union { uint4 u; bf16x8 v; } bf;
                bf.u = smem[rb + bo[t]];
                acc[dy][t] = __builtin_amdgcn_mfma_f32_16x16x32_bf16(
                                 aF[kc], bf.v, acc[dy][t], 0, 0, 0);
            }
        }
        __syncthreads();
    }

    // ---- epilogue: per-wave LDS transpose -> coalesced float4 stores ----
    // 3 chunks of 3 dy; per wave region = 27 rows x pitch 20 floats = 2160B,
    // 16 waves = 34.5KB (fits in the 48KB smem, now free). Pitch 20 keeps rows
    // 16B-aligned (float4) and write banks <=2-way.
    const float inv = 1.0f / 128.0f;
    float* sm = (float*)smem;
    float* ob = out + (size_t)b * 81 * CHS + (size_t)y * Wn + x0s;
    const int wb = w * 540;
    #pragma unroll
    for (int ck = 0; ck < 3; ++ck) {
        #pragma unroll
        for (int d = 0; d < 3; ++d)
            #pragma unroll
            for (int t = 0; t < 2; ++t)
                #pragma unroll
                for (int reg = 0; reg < 4; ++reg) {
                    int mm  = quad * 4 + reg;          // px offset within strip
                    int dxc = 16 * t + n16 - mm - 4;   // displacement channel
                    if (dxc >= 0 && dxc <= 8)
                        sm[wb + (d * 9 + dxc) * 20 + mm] = acc[ck * 3 + d][t][reg] * inv;
                }
        __syncthreads();
        // 27 channel-rows x 4 float4 = 108 slots; 2 rounds over 64 lanes
        #pragma unroll
        for (int ii = 0; ii < 2; ++ii) {
            int slot = lane + ii * 64;
            if (slot < 108) {
                int chn = slot >> 2, g = slot & 3;
                float4 v = *(const float4*)&sm[wb + chn * 20 + 4 * g];
                int ch = (ck * 3 + chn / 9) * 9 + chn % 9;
                *(float4*)(ob + (size_t)ch * CHS + 4 * g) = v;
            }
        }
        __syncthreads();
    }
}

extern "C" void kernel_launch(void* const* d_in, const int* in_sizes, int n_in,
                              void* d_out, int out_size, void* d_ws, size_t ws_size,
                              hipStream_t stream) {
    (void)in_sizes; (void)n_in; (void)d_ws; (void)ws_size; (void)out_size;
    const float* first  = (const float*)d_in[0];
    const float* second = (const float*)d_in[1];
    float* out = (float*)d_out;
    corrfused<<<dim3(Wn / 32, Hn / 8, Bn), dim3(1024, 1, 1), 0, stream>>>(
        first, second, out);
}

// Round 2
// 182.151 us; speedup vs baseline: 1.2045x; 1.1222x over previous
//
#include <hip/hip_runtime.h>
#include <stdint.h>

// Correlation via MFMA. out[b,(dy+4)*9+(dx+4),y,x] = (1/128) sum_c F[c,y,x]*S[c,y+dy,x+dx]
//
// R6: occupancy + XCD-locality rework.
//  Diagnosis from R5 counters: VGPR 64 + ~64 AGPR = 128 unified -> 4 waves/SIMD ->
//  a 16-wave block means EXACTLY 1 resident block/CU: zero cross-block overlap,
//  every gather stall and barrier fully exposed (MfmaUtil 3.4%, VALUBusy 13.5%).
//  - Block halved to 512 threads (8 waves), tile 16px x 8 rows, grid 10x12x8=960.
//    Same per-wave work (acc[9][2], 18 MFMA/chunk); LDS 32KB; staging = exactly
//    4 slots/thread (pow2 decode). With <=128 regs -> 2 independent blocks/CU.
//  - Register diet to guarantee <=128: staging split into two 16-reg half-groups
//    (g0 prefetched across the MFMA phase, g1 loaded inside the staging phase);
//    A-frag gathered per-chunk (4 live regs) instead of all 4 chunks upfront.
//  - Bijective XCD-chunked swizzle (960 = 8*120): XCD k owns image b=k, x-fastest.
//    => output 256B L2 lines (4 x-tiles) merge on one XCD (R5 WRITE was 2.2x ideal),
//    and the 3x fp32 halo re-reads of `second` hit that XCD's L2.
//  - LDS XOR swizzle on oct position unchanged (pitch 128 octs % 8 == 0, pattern
//    stays 8 lanes per 4-bank group on both ds_write_b128 and ds_read_b128).
// LESSON (R2): acc[] only ever indexed by fully-unrolled loop vars.

typedef __attribute__((ext_vector_type(8))) short bf16x8;
typedef __attribute__((ext_vector_type(4))) float f32x4;

constexpr int Bn = 8, Cn = 128, Hn = 96, Wn = 160;
constexpr int CHS = Hn * Wn;

__device__ __forceinline__ uint32_t bf16rne(float f) {
    uint32_t u = __float_as_uint(f);
    return (u + 0x7FFFu + ((u >> 16) & 1u)) >> 16;
}
__device__ __forceinline__ uint32_t pk(float a, float b) {
    return bf16rne(a) | (bf16rne(b) << 16);
}

__global__ __launch_bounds__(512, 4)
void corrfused(const float* __restrict__ first, const float* __restrict__ second,
               float* __restrict__ out)
{
    __shared__ uint4 smem[16 * 32 * 4];   // 32 KB: [row][xw][4 swizzled octs]

    const int tid  = threadIdx.x;
    const int w    = tid >> 6;            // wave = output row r (0..7)
    const int lane = tid & 63;
    const int quad = lane >> 4;
    const int n16  = lane & 15;
    const int r    = w;

    // XCD-chunked bijective swizzle: XCD k gets tiles [k*120, (k+1)*120) = image b=k,
    // ordered x-fastest then y. (Hardware round-robins linear block id across XCDs.)
    const int d    = (int)blockIdx.x + 10 * ((int)blockIdx.y + 12 * (int)blockIdx.z);
    const int tile = (d & 7) * 120 + (d >> 3);
    const int b    = tile / 120;
    const int rem  = tile % 120;
    const int y0   = (rem / 10) * 8;
    const int x0   = (rem % 10) * 16;
    const int y    = y0 + r;

    // ---- staging descriptors: 2048 octs (16 rows x 32 px x 4 q), 4 per thread ----
    // slot (row,xw,q) covers channels 32kc+8q..+7 of second at (y0+row-4, x0+xw-8)
    const float* sb = second + (size_t)b * Cn * CHS;
    int goff[4], lpos[4];
    bool val[4];
    #pragma unroll
    for (int i = 0; i < 4; ++i) {
        int e   = tid + i * 512;
        int row = e >> 7;
        int xw  = (e >> 2) & 31;
        int q   = e & 3;
        int gy  = y0 + row - 4, gx = x0 + xw - 8;
        val[i]  = (gy >= 0) && (gy < Hn) && (gx >= 0) && (gx < Wn);
        goff[i] = val[i] ? (8 * q * CHS + gy * Wn + gx) : 0;   // clamped-safe addr
        lpos[i] = (row * 32 + xw) * 4 + ((q + xw + (xw >> 2)) & 3);
    }

    // ---- B-frag lane offsets (row-invariant part) ----
    int bo[2];
    #pragma unroll
    for (int t = 0; t < 2; ++t) {
        int xwr = 16 * t + n16;
        bo[t] = xwr * 4 + ((quad + xwr + (xwr >> 2)) & 3);
    }

    const float* fp = first + (size_t)b * Cn * CHS + (size_t)y * Wn + x0 + n16;

    f32x4 acc[9][2];
    #pragma unroll
    for (int dy = 0; dy < 9; ++dy)
        #pragma unroll
        for (int t = 0; t < 2; ++t)
            acc[dy][t] = (f32x4){0.f, 0.f, 0.f, 0.f};

    // prologue: half-group g0 (slots 0,1) of chunk 0
    float f0[2][8];
    #pragma unroll
    for (int i = 0; i < 2; ++i)
        #pragma unroll
        for (int j = 0; j < 8; ++j)
            f0[i][j] = sb[goff[i] + (size_t)j * CHS];

    #pragma unroll
    for (int kc = 0; kc < 4; ++kc) {
        // pack + write g0 (prefetched), freeing its regs before g1 is issued
        #pragma unroll
        for (int i = 0; i < 2; ++i) {
            uint4 o;
            o.x = pk(f0[i][0], f0[i][1]); o.y = pk(f0[i][2], f0[i][3]);
            o.z = pk(f0[i][4], f0[i][5]); o.w = pk(f0[i][6], f0[i][7]);
            if (!val[i]) o = make_uint4(0u, 0u, 0u, 0u);
            smem[lpos[i]] = o;
        }
        // g1 (slots 2,3) + this chunk's A-frag dwords
        float f1[2][8], fa[8];
        #pragma unroll
        for (int i = 0; i < 2; ++i)
            #pragma unroll
            for (int j = 0; j < 8; ++j)
                f1[i][j] = sb[goff[2 + i] + (size_t)(32 * kc + j) * CHS];
        #pragma unroll
        for (int j = 0; j < 8; ++j)
            fa[j] = fp[(size_t)(32 * kc + 8 * quad + j) * CHS];
        #pragma unroll
        for (int i = 0; i < 2; ++i) {
            uint4 o;
            o.x = pk(f1[i][0], f1[i][1]); o.y = pk(f1[i][2], f1[i][3]);
            o.z = pk(f1[i][4], f1[i][5]); o.w = pk(f1[i][6], f1[i][7]);
            if (!val[2 + i]) o = make_uint4(0u, 0u, 0u, 0u);
            smem[lpos[2 + i]] = o;
        }
        bf16x8 aF;
        {
            union { uint32_t u[4]; bf16x8 v; } cv;
            cv.u[0] = pk(fa[0], fa[1]); cv.u[1] = pk(fa[2], fa[3]);
            cv.u[2] = pk(fa[4], fa[5]); cv.u[3] = pk(fa[6], fa[7]);
            aF = cv.v;
        }
        __syncthreads();
        // prefetch g0 of next chunk; lands while MFMAs run
        if (kc < 3) {
            #pragma unroll
            for (int i = 0; i < 2; ++i)
                #pragma unroll
                for (int j = 0; j < 8; ++j)
                    f0[i][j] = sb[goff[i] + (size_t)(32 * (kc + 1) + j) * CHS];
        }
        #pragma unroll
        for (int dy = 0; dy < 9; ++dy) {
            const int rb = (r + dy) * 128;        // staged row base (oct units)
            #pragma unroll
            for (int t = 0; t < 2; ++t) {
                union { uint4 u; bf16x8 v; } bf;
                bf.u = smem[rb + bo[t]];
                acc[dy][t] = __builtin_amdgcn_mfma_f32_16x16x32_bf16(
                                 aF, bf.v, acc[dy][t], 0, 0, 0);
            }
        }
        __syncthreads();
    }

    // ---- epilogue: per-wave LDS transpose -> coalesced float4 stores ----
    // 3 chunks of 3 dy; per wave region = 27 rows x pitch 20 floats = 2160B,
    // 8 waves = 17.3KB (fits the 32KB smem, now free).
    const float inv = 1.0f / 128.0f;
    float* sm = (float*)smem;
    float* ob = out + (size_t)b * 81 * CHS + (size_t)y * Wn + x0;
    const int wb = w * 540;
    #pragma unroll
    for (int ck = 0; ck < 3; ++ck) {
        #pragma unroll
        for (int dd = 0; dd < 3; ++dd)
            #pragma unroll
            for (int t = 0; t < 2; ++t)
                #pragma unroll
                for (int reg = 0; reg < 4; ++reg) {
                    int mm  = quad * 4 + reg;          // px offset within strip
                    int dxc = 16 * t + n16 - mm - 4;   // displacement channel
                    if (dxc >= 0 && dxc <= 8)
                        sm[wb + (dd * 9 + dxc) * 20 + mm] = acc[ck * 3 + dd][t][reg] * inv;
                }
        __syncthreads();
        // 27 channel-rows x 4 float4 = 108 slots; 2 rounds over 64 lanes
        #pragma unroll
        for (int ii = 0; ii < 2; ++ii) {
            int slot = lane + ii * 64;
            if (slot < 108) {
                int chn = slot >> 2, g = slot & 3;
                float4 v = *(const float4*)&sm[wb + chn * 20 + 4 * g];
                int ch = (ck * 3 + chn / 9) * 9 + chn % 9;
                *(float4*)(ob + (size_t)ch * CHS + 4 * g) = v;
            }
        }
        __syncthreads();
    }
}

extern "C" void kernel_launch(void* const* d_in, const int* in_sizes, int n_in,
                              void* d_out, int out_size, void* d_ws, size_t ws_size,
                              hipStream_t stream) {
    (void)in_sizes; (void)n_in; (void)d_ws; (void)ws_size; (void)out_size;
    const float* first  = (const float*)d_in[0];
    const float* second = (const float*)d_in[1];
    float* out = (float*)d_out;
    corrfused<<<dim3(Wn / 16, Hn / 8, Bn), dim3(512, 1, 1), 0, stream>>>(
        first, second, out);
}